// Round 8
// baseline (412.921 us; speedup 1.0000x reference)
//
#include <hip/hip_runtime.h>

// PairwiseInteract, round 11: cross the 4-waves/SIMD line.
// Round-10 collapsed the allocation to 68 arch + 64 acc = 132 total regs
// (opaque per-iteration LDS indices stop loop-invariant hoisting) -> 3
// waves/SIMD. The 4-wave step needs total <=128 AND <=40KB LDS/block:
//   1. L3 staging removed from LDS (44 -> 36KB): the deferred L3 runs once
//      per wave post-loop; its W3ext fragments are built straight from
//      global there (same construction -> bit-identical, L2-cached, 1x/wave).
//   2. __launch_bounds__(256,4): cap 128 total. We are 4 regs over -- a gap
//      rematerialization can close (rounds 4/6 failed forcing a ~190-reg
//      structure; this one is measured at 132).
// Tripwire: FETCH>5MB / WRITE>20MB = spill -> revert to (256,2).
// Math identical to rounds 5/10: deferred L3 (forces = (sum_j relu(h2))@W3
// + 16*b3), split-bf16 (hh+hl+lh), f=3 packs specialized, no setprio.

#define NOBJ 1024
#define H 50
#define F 20

using short8 = __attribute__((ext_vector_type(8))) short;
using v16f   = __attribute__((ext_vector_type(16))) float;

#define MFMA(A, B, C) __builtin_amdgcn_mfma_f32_32x32x16_bf16((A), (B), (C), 0, 0, 0)

__device__ __forceinline__ float trunchi(float x) {
    return __uint_as_float(__float_as_uint(x) & 0xFFFF0000u);
}
// dword = hi16(a) in low half | hi16(b) in high half
__device__ __forceinline__ unsigned pkhi(float a, float b) {
    return __builtin_amdgcn_perm(__float_as_uint(b), __float_as_uint(a), 0x07060302u);
}
__device__ __forceinline__ short8 as_s8(uint4 v) {
    union { uint4 u; short8 s; } x; x.u = v; return x.s;
}
// out-neuron at C slot (mt, tile-row l)
__device__ __forceinline__ int nu(int mt, int l) {
    return 16 * (l >> 3) + 8 * ((l >> 2) & 1) + 4 * mt + (l & 3);
}

// full pack for k-frags 0..2 (all 48 neurons real there)
#define PACK_MT3(ACC, MT, XH, XL)                                             \
    _Pragma("unroll") for (int f_ = 0; f_ < 3; ++f_) {                        \
        float r0 = fmaxf((ACC)[4 * f_ + 0], 0.f);                             \
        float r1 = fmaxf((ACC)[4 * f_ + 1], 0.f);                             \
        float r2 = fmaxf((ACC)[4 * f_ + 2], 0.f);                             \
        float r3 = fmaxf((ACC)[4 * f_ + 3], 0.f);                             \
        float l0 = r0 - trunchi(r0), l1 = r1 - trunchi(r1);                   \
        float l2 = r2 - trunchi(r2), l3 = r3 - trunchi(r3);                   \
        ((unsigned*)&(XH)[f_])[2 * (MT) + 0] = pkhi(r0, r1);                  \
        ((unsigned*)&(XH)[f_])[2 * (MT) + 1] = pkhi(r2, r3);                  \
        ((unsigned*)&(XL)[f_])[2 * (MT) + 0] = pkhi(l0, l1);                  \
        ((unsigned*)&(XL)[f_])[2 * (MT) + 1] = pkhi(l2, l3);                  \
    }

// k-frag 3: only k=48,49 (h=0) are live activations; k=50 is the injected
// bias multiplier; k=51..63 statically zero -> 8 ops instead of 32.
#define PACK_F3(ACC0, XH, XL, INJ)                                            \
    {                                                                         \
        float r0_ = fmaxf((ACC0)[12], 0.f);                                   \
        float r1_ = fmaxf((ACC0)[13], 0.f);                                   \
        float l0_ = r0_ - trunchi(r0_), l1_ = r1_ - trunchi(r1_);             \
        (XH)[3].x = pkhi(r0_, r1_); (XL)[3].x = pkhi(l0_, l1_);               \
        (XH)[3].y = (INJ); (XL)[3].y = 0u;                                    \
        (XH)[3].z = 0u; (XH)[3].w = 0u;                                       \
        (XL)[3].z = 0u; (XL)[3].w = 0u;                                       \
    }

#define LDSFRAG(id)  (*(const short8*)&wfrag[(id) * 64 + lane])
// opaque-index variant: obf (==0, but opaque per-iteration) blocks hoist/CSE
#define LDSFRAGO(id) (*(const short8*)&wfrag[((id) + obf) * 64 + lane])

// hidden layer: 2 m-tiles x 4 k-frags x 3 split terms = 24 MFMA
#define LAYER_CHAIN(BASEC, XH, XL, A0, A1)                                    \
    _Pragma("unroll") for (int f_ = 0; f_ < 4; ++f_) {                        \
        short8 ah0 = LDSFRAGO(((BASEC) + f_) * 2 + 0);                        \
        short8 al0 = LDSFRAGO(((BASEC) + f_) * 2 + 1);                        \
        short8 ah1 = LDSFRAGO(((BASEC) + 4 + f_) * 2 + 0);                    \
        short8 al1 = LDSFRAGO(((BASEC) + 4 + f_) * 2 + 1);                    \
        short8 bh = as_s8((XH)[f_]), bl = as_s8((XL)[f_]);                    \
        if (f_ == 0) { A0 = MFMA(ah0, bh, zero16); A1 = MFMA(ah1, bh, zero16); } \
        else         { A0 = MFMA(ah0, bh, A0);     A1 = MFMA(ah1, bh, A1); }  \
        A0 = MFMA(ah0, bl, A0); A1 = MFMA(ah1, bl, A1);                       \
        A0 = MFMA(al0, bh, A0); A1 = MFMA(al1, bh, A1);                       \
    }

__global__ __launch_bounds__(256, 4)
void pair_kernel(const float* __restrict__ obj0, const float* __restrict__ obj1,
                 const float* __restrict__ prev0, const float* __restrict__ prev1,
                 const float* __restrict__ gW0, const float* __restrict__ gb0,
                 const float* __restrict__ gW1, const float* __restrict__ gb1,
                 const float* __restrict__ gW2, const float* __restrict__ gb2,
                 const float* __restrict__ gW3, const float* __restrict__ gb3,
                 float* __restrict__ forces)
{
    // 36 pre-packed A-fragments (L1:0..15, L2:16..31, W0:32..35), 1KB each
    __shared__ uint4 wfrag[36 * 64];

    const int w    = threadIdx.x >> 6;   // wave 0..3
    const int lane = threadIdx.x & 63;
    const int h    = lane >> 5;          // half-wave
    const int l31  = lane & 31;

    const int m = blockIdx.y;            // module
    const int a = m >> 1, c = m & 1;

    const float* actor = (a == 0) ? obj0 : (a == 1) ? obj1 : (a == 2) ? prev0 : prev1;
    const float* actee = (c == 0) ? obj0 : obj1;

    // ---- stage W0/W1/W2 split-bf16 A-fragments into LDS (once per wg) ----
    for (int combo = w; combo < 18; combo += 4) {
        const int layer = (combo < 8) ? 1 : (combo < 16) ? 2 : 0;
        const float* W; const float* b; int ncols, col, mt, f, krows;
        if (layer == 1) {
            const int rel = combo;
            W = gW1 + m * H * H; b = gb1 + m * H; ncols = H; krows = H;
            mt = rel >> 2; f = rel & 3; col = nu(mt, l31);
        } else if (layer == 2) {
            const int rel = combo - 8;
            W = gW2 + m * H * H; b = gb2 + m * H; ncols = H; krows = H;
            mt = rel >> 2; f = rel & 3; col = nu(mt, l31);
        } else {
            const int rel = combo - 16;
            W = gW0 + m * 2 * H; b = gb0 + m * H; ncols = H; krows = 2;
            mt = rel; f = 0; col = nu(mt, l31);
        }
        unsigned hs[8], ls[8];
#pragma unroll
        for (int j = 0; j < 8; ++j) {
            const int k = 16 * f + 8 * h + j;
            float wv = 0.f;
            if (col < ncols) {
                if (k < krows) wv = W[k * ncols + col];
                else if (k == krows) wv = b[col];      // bias row
            }
            unsigned uh = __float_as_uint(wv) & 0xFFFF0000u;
            float lof = wv - __uint_as_float(uh);
            hs[j] = uh;
            ls[j] = __float_as_uint(lof) & 0xFFFF0000u;
        }
        uint4 hi, lo;
        hi.x = (hs[0] >> 16) | hs[1]; hi.y = (hs[2] >> 16) | hs[3];
        hi.z = (hs[4] >> 16) | hs[5]; hi.w = (hs[6] >> 16) | hs[7];
        lo.x = (ls[0] >> 16) | ls[1]; lo.y = (ls[2] >> 16) | ls[3];
        lo.z = (ls[4] >> 16) | ls[5]; lo.w = (ls[6] >> 16) | ls[7];
        wfrag[(combo * 2 + 0) * 64 + lane] = hi;
        wfrag[(combo * 2 + 1) * 64 + lane] = lo;
    }
    __syncthreads();

    // ---- per-wave work: one actee, one j-half (16 tiles of 32 pairs) ----
    const int i  = blockIdx.x * 2 + (w >> 1);
    const int jh = w & 1;
    const float av  = actee[i];
    const float avl = av - trunchi(av);
    const unsigned inj = (h == 0) ? 0x00003F80u : 0u;   // 1.0 bf16 at k=50

    const v16f zero16 = (v16f)0.0f;
    v16f sA0 = (v16f)0.0f, sA1 = (v16f)0.0f;   // sum of relu(h2), C layout

    float xa_cur = actor[jh * 512 + l31];      // prefetched actor value

#pragma unroll 1
    for (int jt = 0; jt < 16; ++jt) {
        // opaque zero: all wfrag addresses depend on it -> no read can be
        // hoisted out of the loop or CSE'd across iterations
        int obf;
        asm volatile("v_mov_b32 %0, 0" : "=v"(obf));

        const float xa = xa_cur;
        xa_cur = actor[jh * 512 + ((jt + 1) & 15) * 32 + l31];  // next tile
        const float xal = xa - trunchi(xa);

        // L0 B operand: k-slots (h=0): 0=actor, 1=actee, 2=1.0(bias), rest pad
        uint4 b0h4, b0l4;
        b0h4.x = pkhi(xa, av);   b0h4.y = 0x00003F80u; b0h4.z = 0u; b0h4.w = 0u;
        b0l4.x = pkhi(xal, avl); b0l4.y = 0u;          b0l4.z = 0u; b0l4.w = 0u;
        const short8 B0h = as_s8(b0h4), B0l = as_s8(b0l4);

        // ---- L0: 6 MFMA, W0ext frags streamed from LDS ----
        const short8 W0h0 = LDSFRAGO(32), W0l0 = LDSFRAGO(33);
        const short8 W0h1 = LDSFRAGO(34), W0l1 = LDSFRAGO(35);
        v16f a0, a1;
        a0 = MFMA(W0h0, B0h, zero16); a1 = MFMA(W0h1, B0h, zero16);
        a0 = MFMA(W0h0, B0l, a0);     a1 = MFMA(W0h1, B0l, a1);
        a0 = MFMA(W0l0, B0h, a0);     a1 = MFMA(W0l1, B0h, a1);

        uint4 X1h[4], X1l[4];
        PACK_MT3(a0, 0, X1h, X1l); PACK_MT3(a1, 1, X1h, X1l);
        PACK_F3(a0, X1h, X1l, inj);

        // ---- L1: 24 MFMA ----
        LAYER_CHAIN(0, X1h, X1l, a0, a1);
        uint4 X2h[4], X2l[4];
        PACK_MT3(a0, 0, X2h, X2l); PACK_MT3(a1, 1, X2h, X2l);
        PACK_F3(a0, X2h, X2l, inj);

        // ---- L2: 24 MFMA ----
        LAYER_CHAIN(8, X2h, X2l, a0, a1);

        // ---- accumulate relu(h2) in fp32 (dead slots skipped statically) ----
#pragma unroll
        for (int r = 0; r < 14; ++r) sA0[r] += fmaxf(a0[r], 0.f);
#pragma unroll
        for (int r = 0; r < 12; ++r) sA1[r] += fmaxf(a1[r], 0.f);
    }

    // ---- deferred L3: once per wave; W3ext frags built from global ----
    const unsigned inj16 = (h == 0) ? 0x00004180u : 0u;   // 16.0 bf16 at k=50
    uint4 X3h[4], X3l[4];
    PACK_MT3(sA0, 0, X3h, X3l); PACK_MT3(sA1, 1, X3h, X3l);
    PACK_F3(sA0, X3h, X3l, inj16);   // 16 tiles/column -> bias x16

    const float* W3p = gW3 + m * H * F;
    const float* b3p = gb3 + m * F;
    v16f fAcc = (v16f)0.0f;
#pragma unroll
    for (int f = 0; f < 4; ++f) {
        // same construction as the old LDS staging -> bit-identical values
        unsigned hs[8], ls[8];
#pragma unroll
        for (int j = 0; j < 8; ++j) {
            const int k = 16 * f + 8 * h + j;
            float wv = 0.f;
            if (l31 < F) {
                if (k < H) wv = W3p[k * F + l31];
                else if (k == H) wv = b3p[l31];        // bias row
            }
            unsigned uh = __float_as_uint(wv) & 0xFFFF0000u;
            float lof = wv - __uint_as_float(uh);
            hs[j] = uh;
            ls[j] = __float_as_uint(lof) & 0xFFFF0000u;
        }
        uint4 hi, lo;
        hi.x = (hs[0] >> 16) | hs[1]; hi.y = (hs[2] >> 16) | hs[3];
        hi.z = (hs[4] >> 16) | hs[5]; hi.w = (hs[6] >> 16) | hs[7];
        lo.x = (ls[0] >> 16) | ls[1]; lo.y = (ls[2] >> 16) | ls[3];
        lo.z = (ls[4] >> 16) | ls[5]; lo.w = (ls[6] >> 16) | ls[7];
        const short8 ah = as_s8(hi), al = as_s8(lo);
        const short8 bh = as_s8(X3h[f]), bl = as_s8(X3l[f]);
        fAcc = MFMA(ah, bh, fAcc);
        fAcc = MFMA(ah, bl, fAcc);
        fAcc = MFMA(al, bh, fAcc);
    }

    // ---- reduce over pairs (columns) and commit ----
    float* dst = forces + (c * NOBJ + i) * F;
#pragma unroll
    for (int r = 0; r < 16; ++r) {
        float v = fAcc[r];
        v += __shfl_xor(v, 1);
        v += __shfl_xor(v, 2);
        v += __shfl_xor(v, 4);
        v += __shfl_xor(v, 8);
        v += __shfl_xor(v, 16);
        const int row = (r & 3) + 8 * (r >> 2) + 4 * h;   // natural L3 out-feature
        if (l31 == 0 && row < F) atomicAdd(dst + row, v);
    }
}

__global__ __launch_bounds__(256)
void apply_kernel(const float* __restrict__ forces,
                  const float* __restrict__ aW0, const float* __restrict__ ab0,
                  const float* __restrict__ aW1, const float* __restrict__ ab1,
                  float* __restrict__ out)
{
    const int t = blockIdx.x * 256 + threadIdx.x;   // 0..2047
    const int c = t >> 10;                          // wave-uniform
    const int i = t & 1023;

    const float* f = forces + (c * NOBJ + i) * F;
    float fin[F];
#pragma unroll
    for (int k = 0; k < F; ++k) fin[k] = f[k];

    const float* __restrict__ w0 = aW0 + c * F * H;   // (20,50)
    const float* __restrict__ b0 = ab0 + c * H;
    const float* __restrict__ w1 = aW1 + c * H;       // (50,1)
    float pred = ab1[c];
#pragma unroll
    for (int o = 0; o < H; ++o) {
        float s = b0[o];
#pragma unroll
        for (int k = 0; k < F; ++k) s = fmaf(fin[k], w0[k * H + o], s);
        pred = fmaf(fmaxf(s, 0.f), w1[o], pred);
    }
    out[t] = pred;
}

extern "C" void kernel_launch(void* const* d_in, const int* in_sizes, int n_in,
                              void* d_out, int out_size, void* d_ws, size_t ws_size,
                              hipStream_t stream) {
    const float* obj0  = (const float*)d_in[0];
    const float* obj1  = (const float*)d_in[1];
    const float* prev0 = (const float*)d_in[2];
    const float* prev1 = (const float*)d_in[3];
    const float* gW0 = (const float*)d_in[4];
    const float* gb0 = (const float*)d_in[5];
    const float* gW1 = (const float*)d_in[6];
    const float* gb1 = (const float*)d_in[7];
    const float* gW2 = (const float*)d_in[8];
    const float* gb2 = (const float*)d_in[9];
    const float* gW3 = (const float*)d_in[10];
    const float* gb3 = (const float*)d_in[11];
    const float* aW0 = (const float*)d_in[12];
    const float* ab0 = (const float*)d_in[13];
    const float* aW1 = (const float*)d_in[14];
    const float* ab1 = (const float*)d_in[15];

    float* forces = (float*)d_ws;   // [2][1024][20] fp32 accumulator
    hipMemsetAsync(forces, 0, 2 * NOBJ * F * sizeof(float), stream);

    dim3 grid(NOBJ / 2, 8);   // i-groups x modules; 4 waves/wg: 2 actees x 2 j-halves
    pair_kernel<<<grid, 256, 0, stream>>>(obj0, obj1, prev0, prev1,
                                          gW0, gb0, gW1, gb1, gW2, gb2, gW3, gb3,
                                          forces);

    apply_kernel<<<8, 256, 0, stream>>>(forces, aW0, ab0, aW1, ab1, (float*)d_out);
}

// Round 9
// 404.281 us; speedup vs baseline: 1.0214x; 1.0214x over previous
//
#include <hip/hip_runtime.h>

// PairwiseInteract, round 12: single fused dispatch.
// r7/r8 lesson: profiled pair_kernel improved 372->350->344us but graded
// total went 405->407->413 -- the ~50-70us gap is inter-dispatch structure
// (memset + pair + apply serialization, launch/drain, 8MB forces atomics).
// Fusion: blockIdx.y = c (2), loop a=0..3 in-block staging module m=2a+c per
// phase. forces[c][i] completes inside one block: fAcc's MFMA C-operand
// accumulates across the 4 a-phases (deferred-L3 across modules), the force
// reduction lands in LDS, and the apply-MLP runs in-block on waves 0/1.
// Deletes: memset dispatch, apply dispatch, forces global round-trip.
// Total staging work unchanged (1024 blocks x 4 = 4096 stagings); grid
// 1024 = exactly 4 blocks/CU, zero tail. In-loop body identical to r8
// (opaque LDS indices -> 120 total regs, 4 waves/SIMD, 36KB wfrag).

#define NOBJ 1024
#define H 50
#define F 20

using short8 = __attribute__((ext_vector_type(8))) short;
using v16f   = __attribute__((ext_vector_type(16))) float;

#define MFMA(A, B, C) __builtin_amdgcn_mfma_f32_32x32x16_bf16((A), (B), (C), 0, 0, 0)

__device__ __forceinline__ float trunchi(float x) {
    return __uint_as_float(__float_as_uint(x) & 0xFFFF0000u);
}
// dword = hi16(a) in low half | hi16(b) in high half
__device__ __forceinline__ unsigned pkhi(float a, float b) {
    return __builtin_amdgcn_perm(__float_as_uint(b), __float_as_uint(a), 0x07060302u);
}
__device__ __forceinline__ short8 as_s8(uint4 v) {
    union { uint4 u; short8 s; } x; x.u = v; return x.s;
}
// out-neuron at C slot (mt, tile-row l)
__device__ __forceinline__ int nu(int mt, int l) {
    return 16 * (l >> 3) + 8 * ((l >> 2) & 1) + 4 * mt + (l & 3);
}

// full pack for k-frags 0..2 (all 48 neurons real there)
#define PACK_MT3(ACC, MT, XH, XL)                                             \
    _Pragma("unroll") for (int f_ = 0; f_ < 3; ++f_) {                        \
        float r0 = fmaxf((ACC)[4 * f_ + 0], 0.f);                             \
        float r1 = fmaxf((ACC)[4 * f_ + 1], 0.f);                             \
        float r2 = fmaxf((ACC)[4 * f_ + 2], 0.f);                             \
        float r3 = fmaxf((ACC)[4 * f_ + 3], 0.f);                             \
        float l0 = r0 - trunchi(r0), l1 = r1 - trunchi(r1);                   \
        float l2 = r2 - trunchi(r2), l3 = r3 - trunchi(r3);                   \
        ((unsigned*)&(XH)[f_])[2 * (MT) + 0] = pkhi(r0, r1);                  \
        ((unsigned*)&(XH)[f_])[2 * (MT) + 1] = pkhi(r2, r3);                  \
        ((unsigned*)&(XL)[f_])[2 * (MT) + 0] = pkhi(l0, l1);                  \
        ((unsigned*)&(XL)[f_])[2 * (MT) + 1] = pkhi(l2, l3);                  \
    }

// k-frag 3: only k=48,49 (h=0) live activations; k=50 = injected bias mult.
#define PACK_F3(ACC0, XH, XL, INJ)                                            \
    {                                                                         \
        float r0_ = fmaxf((ACC0)[12], 0.f);                                   \
        float r1_ = fmaxf((ACC0)[13], 0.f);                                   \
        float l0_ = r0_ - trunchi(r0_), l1_ = r1_ - trunchi(r1_);             \
        (XH)[3].x = pkhi(r0_, r1_); (XL)[3].x = pkhi(l0_, l1_);               \
        (XH)[3].y = (INJ); (XL)[3].y = 0u;                                    \
        (XH)[3].z = 0u; (XH)[3].w = 0u;                                       \
        (XL)[3].z = 0u; (XL)[3].w = 0u;                                       \
    }

#define LDSFRAG(id)  (*(const short8*)&wfrag[(id) * 64 + lane])
// opaque-index variant: obf (==0, but opaque per-iteration) blocks hoist/CSE
#define LDSFRAGO(id) (*(const short8*)&wfrag[((id) + obf) * 64 + lane])

// hidden layer: 2 m-tiles x 4 k-frags x 3 split terms = 24 MFMA
#define LAYER_CHAIN(BASEC, XH, XL, A0, A1)                                    \
    _Pragma("unroll") for (int f_ = 0; f_ < 4; ++f_) {                        \
        short8 ah0 = LDSFRAGO(((BASEC) + f_) * 2 + 0);                        \
        short8 al0 = LDSFRAGO(((BASEC) + f_) * 2 + 1);                        \
        short8 ah1 = LDSFRAGO(((BASEC) + 4 + f_) * 2 + 0);                    \
        short8 al1 = LDSFRAGO(((BASEC) + 4 + f_) * 2 + 1);                    \
        short8 bh = as_s8((XH)[f_]), bl = as_s8((XL)[f_]);                    \
        if (f_ == 0) { A0 = MFMA(ah0, bh, zero16); A1 = MFMA(ah1, bh, zero16); } \
        else         { A0 = MFMA(ah0, bh, A0);     A1 = MFMA(ah1, bh, A1); }  \
        A0 = MFMA(ah0, bl, A0); A1 = MFMA(ah1, bl, A1);                       \
        A0 = MFMA(al0, bh, A0); A1 = MFMA(al1, bh, A1);                       \
    }

__global__ __launch_bounds__(256, 4)
void fused_kernel(const float* __restrict__ obj0, const float* __restrict__ obj1,
                  const float* __restrict__ prev0, const float* __restrict__ prev1,
                  const float* __restrict__ gW0, const float* __restrict__ gb0,
                  const float* __restrict__ gW1, const float* __restrict__ gb1,
                  const float* __restrict__ gW2, const float* __restrict__ gb2,
                  const float* __restrict__ gW3, const float* __restrict__ gb3,
                  const float* __restrict__ aW0, const float* __restrict__ ab0,
                  const float* __restrict__ aW1, const float* __restrict__ ab1,
                  float* __restrict__ out)
{
    // 36 pre-packed A-fragments (L1:0..15, L2:16..31, W0:32..35), 1KB each
    __shared__ uint4 wfrag[36 * 64];
    __shared__ float fbuf[2][F];     // per-block force accumulators

    const int w    = threadIdx.x >> 6;   // wave 0..3
    const int lane = threadIdx.x & 63;
    const int h    = lane >> 5;          // half-wave
    const int l31  = lane & 31;

    const int c  = blockIdx.y;           // actee class
    const int i  = blockIdx.x * 2 + (w >> 1);
    const int jh = w & 1;

    const float* actee = (c == 0) ? obj0 : obj1;
    const float av  = actee[i];
    const float avl = av - trunchi(av);
    const unsigned inj   = (h == 0) ? 0x00003F80u : 0u;   // 1.0 bf16 at k=50
    const unsigned inj16 = (h == 0) ? 0x00004180u : 0u;   // 16.0 bf16 at k=50

    if (threadIdx.x < 2 * F) ((float*)fbuf)[threadIdx.x] = 0.f;

    const v16f zero16 = (v16f)0.0f;
    v16f fAcc = (v16f)0.0f;              // accumulates across all 4 a-phases

#pragma unroll 1
    for (int a = 0; a < 4; ++a) {
        const int m = a * 2 + c;         // module
        const float* actor = (a == 0) ? obj0 : (a == 1) ? obj1
                           : (a == 2) ? prev0 : prev1;

        // ---- stage W0/W1/W2 split-bf16 A-fragments for module m ----
        for (int combo = w; combo < 18; combo += 4) {
            const int layer = (combo < 8) ? 1 : (combo < 16) ? 2 : 0;
            const float* W; const float* b; int ncols, col, mt, f, krows;
            if (layer == 1) {
                const int rel = combo;
                W = gW1 + m * H * H; b = gb1 + m * H; ncols = H; krows = H;
                mt = rel >> 2; f = rel & 3; col = nu(mt, l31);
            } else if (layer == 2) {
                const int rel = combo - 8;
                W = gW2 + m * H * H; b = gb2 + m * H; ncols = H; krows = H;
                mt = rel >> 2; f = rel & 3; col = nu(mt, l31);
            } else {
                const int rel = combo - 16;
                W = gW0 + m * 2 * H; b = gb0 + m * H; ncols = H; krows = 2;
                mt = rel; f = 0; col = nu(mt, l31);
            }
            unsigned hs[8], ls[8];
#pragma unroll
            for (int j = 0; j < 8; ++j) {
                const int k = 16 * f + 8 * h + j;
                float wv = 0.f;
                if (col < ncols) {
                    if (k < krows) wv = W[k * ncols + col];
                    else if (k == krows) wv = b[col];      // bias row
                }
                unsigned uh = __float_as_uint(wv) & 0xFFFF0000u;
                float lof = wv - __uint_as_float(uh);
                hs[j] = uh;
                ls[j] = __float_as_uint(lof) & 0xFFFF0000u;
            }
            uint4 hi, lo;
            hi.x = (hs[0] >> 16) | hs[1]; hi.y = (hs[2] >> 16) | hs[3];
            hi.z = (hs[4] >> 16) | hs[5]; hi.w = (hs[6] >> 16) | hs[7];
            lo.x = (ls[0] >> 16) | ls[1]; lo.y = (ls[2] >> 16) | ls[3];
            lo.z = (ls[4] >> 16) | ls[5]; lo.w = (ls[6] >> 16) | ls[7];
            wfrag[(combo * 2 + 0) * 64 + lane] = hi;
            wfrag[(combo * 2 + 1) * 64 + lane] = lo;
        }
        __syncthreads();                 // staging visible to all waves

        v16f sA0 = (v16f)0.0f, sA1 = (v16f)0.0f;   // sum of relu(h2)
        float xa_cur = actor[jh * 512 + l31];

#pragma unroll 1
        for (int jt = 0; jt < 16; ++jt) {
            // opaque zero: blocks hoist/CSE of wfrag reads across iterations
            int obf;
            asm volatile("v_mov_b32 %0, 0" : "=v"(obf));

            const float xa = xa_cur;
            xa_cur = actor[jh * 512 + ((jt + 1) & 15) * 32 + l31];
            const float xal = xa - trunchi(xa);

            // L0 B operand: k-slots (h=0): 0=actor, 1=actee, 2=1.0(bias)
            uint4 b0h4, b0l4;
            b0h4.x = pkhi(xa, av);   b0h4.y = 0x00003F80u; b0h4.z = 0u; b0h4.w = 0u;
            b0l4.x = pkhi(xal, avl); b0l4.y = 0u;          b0l4.z = 0u; b0l4.w = 0u;
            const short8 B0h = as_s8(b0h4), B0l = as_s8(b0l4);

            // ---- L0: 6 MFMA, W0ext frags streamed from LDS ----
            const short8 W0h0 = LDSFRAGO(32), W0l0 = LDSFRAGO(33);
            const short8 W0h1 = LDSFRAGO(34), W0l1 = LDSFRAGO(35);
            v16f a0, a1;
            a0 = MFMA(W0h0, B0h, zero16); a1 = MFMA(W0h1, B0h, zero16);
            a0 = MFMA(W0h0, B0l, a0);     a1 = MFMA(W0h1, B0l, a1);
            a0 = MFMA(W0l0, B0h, a0);     a1 = MFMA(W0l1, B0h, a1);

            uint4 X1h[4], X1l[4];
            PACK_MT3(a0, 0, X1h, X1l); PACK_MT3(a1, 1, X1h, X1l);
            PACK_F3(a0, X1h, X1l, inj);

            // ---- L1: 24 MFMA ----
            LAYER_CHAIN(0, X1h, X1l, a0, a1);
            uint4 X2h[4], X2l[4];
            PACK_MT3(a0, 0, X2h, X2l); PACK_MT3(a1, 1, X2h, X2l);
            PACK_F3(a0, X2h, X2l, inj);

            // ---- L2: 24 MFMA ----
            LAYER_CHAIN(8, X2h, X2l, a0, a1);

            // ---- accumulate relu(h2) (dead slots skipped statically) ----
#pragma unroll
            for (int r = 0; r < 14; ++r) sA0[r] += fmaxf(a0[r], 0.f);
#pragma unroll
            for (int r = 0; r < 12; ++r) sA1[r] += fmaxf(a1[r], 0.f);
        }

        // ---- deferred L3 for module m: W3ext frags built from global ----
        {
            uint4 X3h[4], X3l[4];
            PACK_MT3(sA0, 0, X3h, X3l); PACK_MT3(sA1, 1, X3h, X3l);
            PACK_F3(sA0, X3h, X3l, inj16);   // 16 tiles/column -> bias x16

            const float* W3p = gW3 + m * H * F;
            const float* b3p = gb3 + m * F;
#pragma unroll
            for (int f = 0; f < 4; ++f) {
                unsigned hs[8], ls[8];
#pragma unroll
                for (int j = 0; j < 8; ++j) {
                    const int k = 16 * f + 8 * h + j;
                    float wv = 0.f;
                    if (l31 < F) {
                        if (k < H) wv = W3p[k * F + l31];
                        else if (k == H) wv = b3p[l31];    // bias row
                    }
                    unsigned uh = __float_as_uint(wv) & 0xFFFF0000u;
                    float lof = wv - __uint_as_float(uh);
                    hs[j] = uh;
                    ls[j] = __float_as_uint(lof) & 0xFFFF0000u;
                }
                uint4 hi, lo;
                hi.x = (hs[0] >> 16) | hs[1]; hi.y = (hs[2] >> 16) | hs[3];
                hi.z = (hs[4] >> 16) | hs[5]; hi.w = (hs[6] >> 16) | hs[7];
                lo.x = (ls[0] >> 16) | ls[1]; lo.y = (ls[2] >> 16) | ls[3];
                lo.z = (ls[4] >> 16) | ls[5]; lo.w = (ls[6] >> 16) | ls[7];
                const short8 ah = as_s8(hi), al = as_s8(lo);
                const short8 bh = as_s8(X3h[f]), bl = as_s8(X3l[f]);
                fAcc = MFMA(ah, bh, fAcc);
                fAcc = MFMA(ah, bl, fAcc);
                fAcc = MFMA(al, bh, fAcc);
            }
        }
        __syncthreads();   // all waves done reading wfrag before restaging
    }

    // ---- reduce fAcc over pairs (columns) into LDS force buffer ----
#pragma unroll
    for (int r = 0; r < 16; ++r) {
        float v = fAcc[r];
        v += __shfl_xor(v, 1);
        v += __shfl_xor(v, 2);
        v += __shfl_xor(v, 4);
        v += __shfl_xor(v, 8);
        v += __shfl_xor(v, 16);
        const int row = (r & 3) + 8 * (r >> 2) + 4 * h;   // L3 out-feature
        if (l31 == 0 && row < F) atomicAdd(&fbuf[w >> 1][row], v);
    }
    __syncthreads();

    // ---- apply MLP in-block: wave 0 -> i_local 0, wave 1 -> i_local 1 ----
    if (w < 2) {
        const int il = w;
        const int io = blockIdx.x * 2 + il;
        const float* __restrict__ w0 = aW0 + c * F * H;   // (20,50)
        const float* __restrict__ b0 = ab0 + c * H;
        const float* __restrict__ w1 = aW1 + c * H;       // (50,1)
        float t = 0.f;
        if (lane < H) {
            float s = b0[lane];
#pragma unroll
            for (int k = 0; k < F; ++k) s = fmaf(fbuf[il][k], w0[k * H + lane], s);
            t = fmaxf(s, 0.f) * w1[lane];
        }
        t += __shfl_xor(t, 1);
        t += __shfl_xor(t, 2);
        t += __shfl_xor(t, 4);
        t += __shfl_xor(t, 8);
        t += __shfl_xor(t, 16);
        t += __shfl_xor(t, 32);
        if (lane == 0) out[c * NOBJ + io] = t + ab1[c];
    }
}

extern "C" void kernel_launch(void* const* d_in, const int* in_sizes, int n_in,
                              void* d_out, int out_size, void* d_ws, size_t ws_size,
                              hipStream_t stream) {
    const float* obj0  = (const float*)d_in[0];
    const float* obj1  = (const float*)d_in[1];
    const float* prev0 = (const float*)d_in[2];
    const float* prev1 = (const float*)d_in[3];
    const float* gW0 = (const float*)d_in[4];
    const float* gb0 = (const float*)d_in[5];
    const float* gW1 = (const float*)d_in[6];
    const float* gb1 = (const float*)d_in[7];
    const float* gW2 = (const float*)d_in[8];
    const float* gb2 = (const float*)d_in[9];
    const float* gW3 = (const float*)d_in[10];
    const float* gb3 = (const float*)d_in[11];
    const float* aW0 = (const float*)d_in[12];
    const float* ab0 = (const float*)d_in[13];
    const float* aW1 = (const float*)d_in[14];
    const float* ab1 = (const float*)d_in[15];

    dim3 grid(NOBJ / 2, 2);   // i-groups x actee class; 4 waves: 2 i x 2 j-halves
    fused_kernel<<<grid, 256, 0, stream>>>(obj0, obj1, prev0, prev1,
                                           gW0, gb0, gW1, gb1, gW2, gb2,
                                           gW3, gb3, aW0, ab0, aW1, ab1,
                                           (float*)d_out);
}

// Round 10
// 403.239 us; speedup vs baseline: 1.0240x; 1.0026x over previous
//
#include <hip/hip_runtime.h>

// PairwiseInteract, round 13: fused kernel + per-phase force reduction.
// r12 post-mortem: fusing dropped occupancy 41->32% because fAcc (16 AGPR)
// became live ACROSS the 4 a-phases: acc = sA(32)+a0/a1(32)+fAcc(16) = 80,
// total 144 > 128 -> 3 waves/SIMD. Fix: reduce each phase's L3 output into
// the LDS fbuf INSIDE the phase (shfl + LDS atomicAdd); fAcc becomes
// phase-transient, overlapping a0/a1's dead range -> acc 64, total 128 ->
// 4 waves/SIMD restored. Numerics: module-sum order becomes atomic-arbitrary
// (same as r11's global atomics, passed at 0.0625).
// Structure otherwise = r12: single dispatch, blockIdx.y = actee class,
// a-loop staging module m=2a+c (36KB wfrag, opaque LDS indices), deferred
// per-module L3 from global, in-block apply MLP.

#define NOBJ 1024
#define H 50
#define F 20

using short8 = __attribute__((ext_vector_type(8))) short;
using v16f   = __attribute__((ext_vector_type(16))) float;

#define MFMA(A, B, C) __builtin_amdgcn_mfma_f32_32x32x16_bf16((A), (B), (C), 0, 0, 0)

__device__ __forceinline__ float trunchi(float x) {
    return __uint_as_float(__float_as_uint(x) & 0xFFFF0000u);
}
// dword = hi16(a) in low half | hi16(b) in high half
__device__ __forceinline__ unsigned pkhi(float a, float b) {
    return __builtin_amdgcn_perm(__float_as_uint(b), __float_as_uint(a), 0x07060302u);
}
__device__ __forceinline__ short8 as_s8(uint4 v) {
    union { uint4 u; short8 s; } x; x.u = v; return x.s;
}
// out-neuron at C slot (mt, tile-row l)
__device__ __forceinline__ int nu(int mt, int l) {
    return 16 * (l >> 3) + 8 * ((l >> 2) & 1) + 4 * mt + (l & 3);
}

// full pack for k-frags 0..2 (all 48 neurons real there)
#define PACK_MT3(ACC, MT, XH, XL)                                             \
    _Pragma("unroll") for (int f_ = 0; f_ < 3; ++f_) {                        \
        float r0 = fmaxf((ACC)[4 * f_ + 0], 0.f);                             \
        float r1 = fmaxf((ACC)[4 * f_ + 1], 0.f);                             \
        float r2 = fmaxf((ACC)[4 * f_ + 2], 0.f);                             \
        float r3 = fmaxf((ACC)[4 * f_ + 3], 0.f);                             \
        float l0 = r0 - trunchi(r0), l1 = r1 - trunchi(r1);                   \
        float l2 = r2 - trunchi(r2), l3 = r3 - trunchi(r3);                   \
        ((unsigned*)&(XH)[f_])[2 * (MT) + 0] = pkhi(r0, r1);                  \
        ((unsigned*)&(XH)[f_])[2 * (MT) + 1] = pkhi(r2, r3);                  \
        ((unsigned*)&(XL)[f_])[2 * (MT) + 0] = pkhi(l0, l1);                  \
        ((unsigned*)&(XL)[f_])[2 * (MT) + 1] = pkhi(l2, l3);                  \
    }

// k-frag 3: only k=48,49 (h=0) live activations; k=50 = injected bias mult.
#define PACK_F3(ACC0, XH, XL, INJ)                                            \
    {                                                                         \
        float r0_ = fmaxf((ACC0)[12], 0.f);                                   \
        float r1_ = fmaxf((ACC0)[13], 0.f);                                   \
        float l0_ = r0_ - trunchi(r0_), l1_ = r1_ - trunchi(r1_);             \
        (XH)[3].x = pkhi(r0_, r1_); (XL)[3].x = pkhi(l0_, l1_);               \
        (XH)[3].y = (INJ); (XL)[3].y = 0u;                                    \
        (XH)[3].z = 0u; (XH)[3].w = 0u;                                       \
        (XL)[3].z = 0u; (XL)[3].w = 0u;                                       \
    }

#define LDSFRAG(id)  (*(const short8*)&wfrag[(id) * 64 + lane])
// opaque-index variant: obf (==0, but opaque per-iteration) blocks hoist/CSE
#define LDSFRAGO(id) (*(const short8*)&wfrag[((id) + obf) * 64 + lane])

// hidden layer: 2 m-tiles x 4 k-frags x 3 split terms = 24 MFMA
#define LAYER_CHAIN(BASEC, XH, XL, A0, A1)                                    \
    _Pragma("unroll") for (int f_ = 0; f_ < 4; ++f_) {                        \
        short8 ah0 = LDSFRAGO(((BASEC) + f_) * 2 + 0);                        \
        short8 al0 = LDSFRAGO(((BASEC) + f_) * 2 + 1);                        \
        short8 ah1 = LDSFRAGO(((BASEC) + 4 + f_) * 2 + 0);                    \
        short8 al1 = LDSFRAGO(((BASEC) + 4 + f_) * 2 + 1);                    \
        short8 bh = as_s8((XH)[f_]), bl = as_s8((XL)[f_]);                    \
        if (f_ == 0) { A0 = MFMA(ah0, bh, zero16); A1 = MFMA(ah1, bh, zero16); } \
        else         { A0 = MFMA(ah0, bh, A0);     A1 = MFMA(ah1, bh, A1); }  \
        A0 = MFMA(ah0, bl, A0); A1 = MFMA(ah1, bl, A1);                       \
        A0 = MFMA(al0, bh, A0); A1 = MFMA(al1, bh, A1);                       \
    }

__global__ __launch_bounds__(256, 4)
void fused_kernel(const float* __restrict__ obj0, const float* __restrict__ obj1,
                  const float* __restrict__ prev0, const float* __restrict__ prev1,
                  const float* __restrict__ gW0, const float* __restrict__ gb0,
                  const float* __restrict__ gW1, const float* __restrict__ gb1,
                  const float* __restrict__ gW2, const float* __restrict__ gb2,
                  const float* __restrict__ gW3, const float* __restrict__ gb3,
                  const float* __restrict__ aW0, const float* __restrict__ ab0,
                  const float* __restrict__ aW1, const float* __restrict__ ab1,
                  float* __restrict__ out)
{
    // 36 pre-packed A-fragments (L1:0..15, L2:16..31, W0:32..35), 1KB each
    __shared__ uint4 wfrag[36 * 64];
    __shared__ float fbuf[2][F];     // per-block force accumulators

    const int w    = threadIdx.x >> 6;   // wave 0..3
    const int lane = threadIdx.x & 63;
    const int h    = lane >> 5;          // half-wave
    const int l31  = lane & 31;

    const int c  = blockIdx.y;           // actee class
    const int i  = blockIdx.x * 2 + (w >> 1);
    const int jh = w & 1;

    const float* actee = (c == 0) ? obj0 : obj1;
    const float av  = actee[i];
    const float avl = av - trunchi(av);
    const unsigned inj   = (h == 0) ? 0x00003F80u : 0u;   // 1.0 bf16 at k=50
    const unsigned inj16 = (h == 0) ? 0x00004180u : 0u;   // 16.0 bf16 at k=50

    if (threadIdx.x < 2 * F) ((float*)fbuf)[threadIdx.x] = 0.f;

    const v16f zero16 = (v16f)0.0f;

#pragma unroll 1
    for (int a = 0; a < 4; ++a) {
        const int m = a * 2 + c;         // module
        const float* actor = (a == 0) ? obj0 : (a == 1) ? obj1
                           : (a == 2) ? prev0 : prev1;

        // ---- stage W0/W1/W2 split-bf16 A-fragments for module m ----
        for (int combo = w; combo < 18; combo += 4) {
            const int layer = (combo < 8) ? 1 : (combo < 16) ? 2 : 0;
            const float* W; const float* b; int ncols, col, mt, f, krows;
            if (layer == 1) {
                const int rel = combo;
                W = gW1 + m * H * H; b = gb1 + m * H; ncols = H; krows = H;
                mt = rel >> 2; f = rel & 3; col = nu(mt, l31);
            } else if (layer == 2) {
                const int rel = combo - 8;
                W = gW2 + m * H * H; b = gb2 + m * H; ncols = H; krows = H;
                mt = rel >> 2; f = rel & 3; col = nu(mt, l31);
            } else {
                const int rel = combo - 16;
                W = gW0 + m * 2 * H; b = gb0 + m * H; ncols = H; krows = 2;
                mt = rel; f = 0; col = nu(mt, l31);
            }
            unsigned hs[8], ls[8];
#pragma unroll
            for (int j = 0; j < 8; ++j) {
                const int k = 16 * f + 8 * h + j;
                float wv = 0.f;
                if (col < ncols) {
                    if (k < krows) wv = W[k * ncols + col];
                    else if (k == krows) wv = b[col];      // bias row
                }
                unsigned uh = __float_as_uint(wv) & 0xFFFF0000u;
                float lof = wv - __uint_as_float(uh);
                hs[j] = uh;
                ls[j] = __float_as_uint(lof) & 0xFFFF0000u;
            }
            uint4 hi, lo;
            hi.x = (hs[0] >> 16) | hs[1]; hi.y = (hs[2] >> 16) | hs[3];
            hi.z = (hs[4] >> 16) | hs[5]; hi.w = (hs[6] >> 16) | hs[7];
            lo.x = (ls[0] >> 16) | ls[1]; lo.y = (ls[2] >> 16) | ls[3];
            lo.z = (ls[4] >> 16) | ls[5]; lo.w = (ls[6] >> 16) | ls[7];
            wfrag[(combo * 2 + 0) * 64 + lane] = hi;
            wfrag[(combo * 2 + 1) * 64 + lane] = lo;
        }
        __syncthreads();                 // staging visible to all waves

        v16f sA0 = (v16f)0.0f, sA1 = (v16f)0.0f;   // sum of relu(h2)
        float xa_cur = actor[jh * 512 + l31];

#pragma unroll 1
        for (int jt = 0; jt < 16; ++jt) {
            // opaque zero: blocks hoist/CSE of wfrag reads across iterations
            int obf;
            asm volatile("v_mov_b32 %0, 0" : "=v"(obf));

            const float xa = xa_cur;
            xa_cur = actor[jh * 512 + ((jt + 1) & 15) * 32 + l31];
            const float xal = xa - trunchi(xa);

            // L0 B operand: k-slots (h=0): 0=actor, 1=actee, 2=1.0(bias)
            uint4 b0h4, b0l4;
            b0h4.x = pkhi(xa, av);   b0h4.y = 0x00003F80u; b0h4.z = 0u; b0h4.w = 0u;
            b0l4.x = pkhi(xal, avl); b0l4.y = 0u;          b0l4.z = 0u; b0l4.w = 0u;
            const short8 B0h = as_s8(b0h4), B0l = as_s8(b0l4);

            // ---- L0: 6 MFMA, W0ext frags streamed from LDS ----
            const short8 W0h0 = LDSFRAGO(32), W0l0 = LDSFRAGO(33);
            const short8 W0h1 = LDSFRAGO(34), W0l1 = LDSFRAGO(35);
            v16f a0, a1;
            a0 = MFMA(W0h0, B0h, zero16); a1 = MFMA(W0h1, B0h, zero16);
            a0 = MFMA(W0h0, B0l, a0);     a1 = MFMA(W0h1, B0l, a1);
            a0 = MFMA(W0l0, B0h, a0);     a1 = MFMA(W0l1, B0h, a1);

            uint4 X1h[4], X1l[4];
            PACK_MT3(a0, 0, X1h, X1l); PACK_MT3(a1, 1, X1h, X1l);
            PACK_F3(a0, X1h, X1l, inj);

            // ---- L1: 24 MFMA ----
            LAYER_CHAIN(0, X1h, X1l, a0, a1);
            uint4 X2h[4], X2l[4];
            PACK_MT3(a0, 0, X2h, X2l); PACK_MT3(a1, 1, X2h, X2l);
            PACK_F3(a0, X2h, X2l, inj);

            // ---- L2: 24 MFMA ----
            LAYER_CHAIN(8, X2h, X2l, a0, a1);

            // ---- accumulate relu(h2) (dead slots skipped statically) ----
#pragma unroll
            for (int r = 0; r < 14; ++r) sA0[r] += fmaxf(a0[r], 0.f);
#pragma unroll
            for (int r = 0; r < 12; ++r) sA1[r] += fmaxf(a1[r], 0.f);
        }

        // ---- deferred L3 for module m (fAcc PHASE-TRANSIENT) ----
        {
            uint4 X3h[4], X3l[4];
            PACK_MT3(sA0, 0, X3h, X3l); PACK_MT3(sA1, 1, X3h, X3l);
            PACK_F3(sA0, X3h, X3l, inj16);   // 16 tiles/column -> bias x16

            const float* W3p = gW3 + m * H * F;
            const float* b3p = gb3 + m * F;
            v16f fAcc = (v16f)0.0f;
#pragma unroll
            for (int f = 0; f < 4; ++f) {
                unsigned hs[8], ls[8];
#pragma unroll
                for (int j = 0; j < 8; ++j) {
                    const int k = 16 * f + 8 * h + j;
                    float wv = 0.f;
                    if (l31 < F) {
                        if (k < H) wv = W3p[k * F + l31];
                        else if (k == H) wv = b3p[l31];    // bias row
                    }
                    unsigned uh = __float_as_uint(wv) & 0xFFFF0000u;
                    float lof = wv - __uint_as_float(uh);
                    hs[j] = uh;
                    ls[j] = __float_as_uint(lof) & 0xFFFF0000u;
                }
                uint4 hi, lo;
                hi.x = (hs[0] >> 16) | hs[1]; hi.y = (hs[2] >> 16) | hs[3];
                hi.z = (hs[4] >> 16) | hs[5]; hi.w = (hs[6] >> 16) | hs[7];
                lo.x = (ls[0] >> 16) | ls[1]; lo.y = (ls[2] >> 16) | ls[3];
                lo.z = (ls[4] >> 16) | ls[5]; lo.w = (ls[6] >> 16) | ls[7];
                const short8 ah = as_s8(hi), al = as_s8(lo);
                const short8 bh = as_s8(X3h[f]), bl = as_s8(X3l[f]);
                fAcc = MFMA(ah, bh, fAcc);
                fAcc = MFMA(ah, bl, fAcc);
                fAcc = MFMA(al, bh, fAcc);
            }

            // reduce this module's contribution into the LDS force buffer
#pragma unroll
            for (int r = 0; r < 16; ++r) {
                float v = fAcc[r];
                v += __shfl_xor(v, 1);
                v += __shfl_xor(v, 2);
                v += __shfl_xor(v, 4);
                v += __shfl_xor(v, 8);
                v += __shfl_xor(v, 16);
                const int row = (r & 3) + 8 * (r >> 2) + 4 * h;  // L3 feature
                if (l31 == 0 && row < F) atomicAdd(&fbuf[w >> 1][row], v);
            }
        }
        __syncthreads();   // atomics done + wfrag free before restaging
    }

    // ---- apply MLP in-block: wave 0 -> i_local 0, wave 1 -> i_local 1 ----
    if (w < 2) {
        const int il = w;
        const int io = blockIdx.x * 2 + il;
        const float* __restrict__ w0 = aW0 + c * F * H;   // (20,50)
        const float* __restrict__ b0 = ab0 + c * H;
        const float* __restrict__ w1 = aW1 + c * H;       // (50,1)
        float t = 0.f;
        if (lane < H) {
            float s = b0[lane];
#pragma unroll
            for (int k = 0; k < F; ++k) s = fmaf(fbuf[il][k], w0[k * H + lane], s);
            t = fmaxf(s, 0.f) * w1[lane];
        }
        t += __shfl_xor(t, 1);
        t += __shfl_xor(t, 2);
        t += __shfl_xor(t, 4);
        t += __shfl_xor(t, 8);
        t += __shfl_xor(t, 16);
        t += __shfl_xor(t, 32);
        if (lane == 0) out[c * NOBJ + io] = t + ab1[c];
    }
}

extern "C" void kernel_launch(void* const* d_in, const int* in_sizes, int n_in,
                              void* d_out, int out_size, void* d_ws, size_t ws_size,
                              hipStream_t stream) {
    const float* obj0  = (const float*)d_in[0];
    const float* obj1  = (const float*)d_in[1];
    const float* prev0 = (const float*)d_in[2];
    const float* prev1 = (const float*)d_in[3];
    const float* gW0 = (const float*)d_in[4];
    const float* gb0 = (const float*)d_in[5];
    const float* gW1 = (const float*)d_in[6];
    const float* gb1 = (const float*)d_in[7];
    const float* gW2 = (const float*)d_in[8];
    const float* gb2 = (const float*)d_in[9];
    const float* gW3 = (const float*)d_in[10];
    const float* gb3 = (const float*)d_in[11];
    const float* aW0 = (const float*)d_in[12];
    const float* ab0 = (const float*)d_in[13];
    const float* aW1 = (const float*)d_in[14];
    const float* ab1 = (const float*)d_in[15];

    dim3 grid(NOBJ / 2, 2);   // i-groups x actee class; 4 waves: 2 i x 2 j-halves
    fused_kernel<<<grid, 256, 0, stream>>>(obj0, obj1, prev0, prev1,
                                           gW0, gb0, gW1, gb1, gW2, gb2,
                                           gW3, gb3, aW0, ab0, aW1, ab1,
                                           (float*)d_out);
}